// Round 6
// baseline (301.516 us; speedup 1.0000x reference)
//
#include <hip/hip_runtime.h>
#include <hip/hip_bf16.h>
#include <math.h>

// R6: attention -> two barrier-free streaming kernels.
//   k_attn_qk: per-wave (b,h,m16): ein1 full-n MFMA, LIF state in regs, spikes
//              packed to u64 bit-words in global (abits) - coalesced, no LDS pb.
//   k_attn_pv: per-wave (b,h,m16): 16B bit-load + in-reg expand to B-frags,
//              ein2 MFMA, out-LIF in regs. No LDS, no barriers.
//   The C/D->B-frag "transpose" is pure addressing on the bit-words.
// Other kernels unchanged.

typedef __attribute__((ext_vector_type(8))) short short8;
typedef __attribute__((ext_vector_type(4))) float f32x4;

#define T_ 4
#define B_ 4
#define C_ 384
#define HW 1024
#define NH_ 12
#define Np_ 256
#define EPS_ 1e-5f
#define LDK 56

static __device__ __forceinline__ unsigned short f2bf(float f) {
    __hip_bfloat16 h = __float2bfloat16(f);
    return *reinterpret_cast<unsigned short*>(&h);
}
static __device__ __forceinline__ float bf2f(unsigned short u) {
    __hip_bfloat16 h = *reinterpret_cast<__hip_bfloat16*>(&u);
    return __bfloat162float(h);
}
static __device__ __forceinline__ void split3(float w, unsigned short& u0,
                                              unsigned short& u1, unsigned short& u2) {
    u0 = f2bf(w);  float f0 = bf2f(u0);
    float r1 = w - f0;
    u1 = f2bf(r1); float f1 = bf2f(u1);
    u2 = f2bf(r1 - f1);
}

// ---------------- K0: weight 3-way bf16 split ----------------
__global__ __launch_bounds__(256) void k_wsplit(const float* __restrict__ Wc,
                                                const float* __restrict__ Wp,
                                                unsigned short* __restrict__ Wc3,
                                                unsigned short* __restrict__ Wp3) {
    const int NC = 768 * 1536;
    const int NP = 384 * 384;
    int i = blockIdx.x * 256 + threadIdx.x;
    float w; unsigned short* dst; int idx, plane;
    if (i < NC) { w = Wc[i]; dst = Wc3; idx = i; plane = NC; }
    else {
        int j = i - NC;
        if (j >= NP) return;
        w = Wp[j]; dst = Wp3; idx = j; plane = NP;
    }
    unsigned short u0, u1, u2;
    split3(w, u0, u1, u2);
    dst[idx] = u0; dst[plane + idx] = u1; dst[2 * plane + idx] = u2;
}

// ---------------- K1: LIF(x) fused with im2col -> Bc[n][k] bf16, + xsb[tb][c][hw] bf16 ----
__global__ __launch_bounds__(256) void k_lif_im2col(const float* __restrict__ x,
                                                    unsigned short* __restrict__ Bc,
                                                    unsigned short* __restrict__ xsb) {
    int gt = blockIdx.x * 256 + threadIdx.x;
    int pw = gt & 15, ph = (gt >> 4) & 15;
    int v = gt >> 8;
    int c = v % 384, b = v / 384;
    float v00 = 0.f, v01 = 0.f, v10 = 0.f, v11 = 0.f;
    const size_t xrow = ((size_t)b * C_ + c) * HW + (size_t)(2 * ph) * 32 + 2 * pw;
#pragma unroll
    for (int t = 0; t < T_; ++t) {
        const float* px = x + (size_t)t * (B_ * C_ * HW) + xrow;
        float2 r0 = *(const float2*)px;
        float2 r1 = *(const float2*)(px + 32);
        v00 += (r0.x - v00) * 0.5f;
        v01 += (r0.y - v01) * 0.5f;
        v10 += (r1.x - v10) * 0.5f;
        v11 += (r1.y - v11) * 0.5f;
        ushort4 s;
        s.x = (v00 >= 1.f) ? 0x3F80 : 0; if (v00 >= 1.f) v00 = 0.f;
        s.y = (v01 >= 1.f) ? 0x3F80 : 0; if (v01 >= 1.f) v01 = 0.f;
        s.z = (v10 >= 1.f) ? 0x3F80 : 0; if (v10 >= 1.f) v10 = 0.f;
        s.w = (v11 >= 1.f) ? 0x3F80 : 0; if (v11 >= 1.f) v11 = 0.f;
        int tb = t * B_ + b;
        int n = tb * 256 + ph * 16 + pw;
        *(ushort4*)(Bc + (size_t)n * 1536 + 4 * c) = s;
        size_t xo = ((size_t)tb * C_ + c) * HW + (size_t)(2 * ph) * 32 + 2 * pw;
        ushort2 w0 = {s.x, s.y}, w1 = {s.z, s.w};
        *(ushort2*)(xsb + xo) = w0;
        *(ushort2*)(xsb + xo + 32) = w1;
    }
}

// ---------------- K2: conv GEMM via MFMA; epilogue emits scaled 3-split y1s/y2s ----------
__global__ __launch_bounds__(256) void k_mconv(const unsigned short* __restrict__ Bc,
                                               const unsigned short* __restrict__ Wc3,
                                               const float* __restrict__ g1,
                                               const float* __restrict__ b1,
                                               const float* __restrict__ frx,
                                               const float* __restrict__ fra,
                                               unsigned short* __restrict__ y1s,
                                               unsigned short* __restrict__ y2s) {
    __shared__ short As[3][64][LDK];
    __shared__ short Bs[128][LDK];
    const int nb = blockIdx.x, mb = blockIdx.y;
    const int tid = threadIdx.x;
    const int lane = tid & 63, wave = tid >> 6;
    const int wm = wave >> 1, wn = wave & 1;
    const int quad = lane >> 4, lr = lane & 15;
    const int arow = tid >> 2, akoff = (tid & 3) * 8;
    f32x4 acc[2][4];
#pragma unroll
    for (int im = 0; im < 2; ++im)
#pragma unroll
        for (int in = 0; in < 4; ++in)
            acc[im][in] = (f32x4){0.f, 0.f, 0.f, 0.f};

    for (int k0 = 0; k0 < 1536; k0 += 32) {
#pragma unroll
        for (int s = 0; s < 3; ++s) {
            short8 a = *(const short8*)(Wc3 + ((size_t)(s * 768 + mb * 64 + arow)) * 1536 + k0 + akoff);
            *(short8*)&As[s][arow][akoff] = a;
        }
#pragma unroll
        for (int i = 0; i < 2; ++i) {
            int f = i * 256 + tid;
            int row = f >> 2, koff = (f & 3) * 8;
            short8 bv = *(const short8*)(Bc + ((size_t)(nb * 128 + row)) * 1536 + k0 + koff);
            *(short8*)&Bs[row][koff] = bv;
        }
        __syncthreads();
        short8 bf[4], af[3][2];
#pragma unroll
        for (int in = 0; in < 4; ++in)
            bf[in] = *(const short8*)&Bs[wn * 64 + in * 16 + lr][quad * 8];
#pragma unroll
        for (int s = 0; s < 3; ++s)
#pragma unroll
            for (int im = 0; im < 2; ++im)
                af[s][im] = *(const short8*)&As[s][wm * 32 + im * 16 + lr][quad * 8];
#pragma unroll
        for (int s = 0; s < 3; ++s)
#pragma unroll
            for (int im = 0; im < 2; ++im)
#pragma unroll
                for (int in = 0; in < 4; ++in)
                    acc[im][in] = __builtin_amdgcn_mfma_f32_16x16x32_bf16(af[s][im], bf[in], acc[im][in], 0, 0, 0);
        __syncthreads();
    }
    const float rs = 1.0f / sqrtf(1.0f + EPS_);
    const int h = mb;
    const float scl = (wm == 0) ? (1.0f / sqrtf(frx[h] * 32.0f))
                                : (1.0f / sqrtf(fra[h] * 256.0f));
    unsigned short* dst = (wm == 0) ? y1s : y2s;
#pragma unroll
    for (int im = 0; im < 2; ++im) {
#pragma unroll
        for (int in = 0; in < 4; ++in) {
            int n_g = nb * 128 + wn * 64 + in * 16 + lr;
            int tb = n_g >> 8, pn = n_g & 255;
            size_t base = (size_t)(tb * NH_ + h) * 3 * 8192;
            ushort4 o0, o1, o2;
#pragma unroll
            for (int r = 0; r < 4; ++r) {
                int oc = mb * 64 + wm * 32 + im * 16 + quad * 4 + r;
                float val = (acc[im][in][r] * (g1[oc] * rs) + b1[oc]) * scl;
                unsigned short u0, u1, u2;
                split3(val, u0, u1, u2);
                ((unsigned short*)&o0)[r] = u0;
                ((unsigned short*)&o1)[r] = u1;
                ((unsigned short*)&o2)[r] = u2;
            }
            int dd = im * 16 + quad * 4;
            if (wm == 0) {
                *(ushort4*)&dst[base + 0 * 8192 + (size_t)pn * 32 + dd] = o0;
                *(ushort4*)&dst[base + 1 * 8192 + (size_t)pn * 32 + dd] = o1;
                *(ushort4*)&dst[base + 2 * 8192 + (size_t)pn * 32 + dd] = o2;
            } else {
#pragma unroll
                for (int r = 0; r < 4; ++r) {
                    dst[base + 0 * 8192 + (size_t)(dd + r) * 256 + pn] = ((unsigned short*)&o0)[r];
                    dst[base + 1 * 8192 + (size_t)(dd + r) * 256 + pn] = ((unsigned short*)&o1)[r];
                    dst[base + 2 * 8192 + (size_t)(dd + r) * 256 + pn] = ((unsigned short*)&o2)[r];
                }
            }
        }
    }
}

// ---------------- K3a: ein1 + attn-LIF -> packed spike bits ----------------
// Wave owns (b,h, m-tile of 16). Lane (quad,lr): attn column m=m0+wv*16+lr,
// rows n = it*16 + quad*4 + r. Bit idx in u64 = it*4+r. abits[tbh][m][quad].
__global__ __launch_bounds__(256, 2) void k_attn_qk(const unsigned short* __restrict__ xsb,
                                                    const unsigned short* __restrict__ y1s,
                                                    unsigned long long* __restrict__ abits) {
    __shared__ unsigned short xb[4][64][40];   // [t][m][d] : 20,480 B
    const int h = blockIdx.y, b = blockIdx.z;
    const int tid = threadIdx.x;
    const int lane = tid & 63, wv = tid >> 6;
    const int quad = lane >> 4, lr = lane & 15;
    const int m0 = blockIdx.x * 64;
    const int mloc = wv * 16 + lr;

#pragma unroll
    for (int i = 0; i < 8; ++i) {
        int e = tid + i * 256;                 // 2048 ushort4 = 4t*64m*32d
        int j4 = e & 15, d = (e >> 4) & 31, t = e >> 9;
        ushort4 v = *(const ushort4*)(xsb + ((size_t)((t * B_ + b) * C_) + h * 32 + d) * HW + m0 + j4 * 4);
        xb[t][j4 * 4 + 0][d] = v.x;
        xb[t][j4 * 4 + 1][d] = v.y;
        xb[t][j4 * 4 + 2][d] = v.z;
        xb[t][j4 * 4 + 3][d] = v.w;
    }
    __syncthreads();   // the only barrier; t-loop below is wave-autonomous

    float vat[16][4];
#pragma unroll
    for (int it = 0; it < 16; ++it)
#pragma unroll
        for (int r = 0; r < 4; ++r) vat[it][r] = 0.f;

    for (int t = 0; t < T_; ++t) {
        const int tb = t * B_ + b;
        const size_t slab = (size_t)(tb * NH_ + h) * 3 * 8192;
        short8 bx = *(const short8*)&xb[t][mloc][quad * 8];

        f32x4 acc[16];
#pragma unroll
        for (int it = 0; it < 16; ++it) acc[it] = (f32x4){0.f, 0.f, 0.f, 0.f};
        const unsigned short* y1p = y1s + slab + (size_t)lr * 32 + quad * 8;
#pragma unroll
        for (int s = 0; s < 3; ++s)
#pragma unroll
            for (int it = 0; it < 16; ++it) {
                short8 a = *(const short8*)(y1p + s * 8192 + it * 512);
                acc[it] = __builtin_amdgcn_mfma_f32_16x16x32_bf16(a, bx, acc[it], 0, 0, 0);
            }

        unsigned int q0 = 0, q1 = 0;
#pragma unroll
        for (int it = 0; it < 16; ++it)
#pragma unroll
            for (int r = 0; r < 4; ++r) {
                float v = vat[it][r];
                v += (acc[it][r] - v) * 0.5f;
                bool s = (v >= 1.0f);
                vat[it][r] = s ? 0.f : v;
                unsigned int sb = s ? 1u : 0u;
                int bit = it * 4 + r;
                if (bit < 32) q0 |= sb << bit;
                else          q1 |= sb << (bit - 32);
            }
        unsigned long long Av = ((unsigned long long)q1 << 32) | q0;
        abits[((size_t)(tb * NH_ + h) * 1024 + m0 + mloc) * 4 + quad] = Av;
    }
}

// ---------------- K3b: ein2 + out-LIF (no LDS, no barriers) ----------------
// Lane (quad,lr): needs attn bits n = kt*32+quad*8+j of column m.
// Source word = abits[m][(quad&1)*2 + (j>=4)], bit = kt*8 + (quad&2)*2 + (j&3).
__global__ __launch_bounds__(256, 4) void k_attn_pv(const unsigned long long* __restrict__ abits,
                                                    const unsigned short* __restrict__ y2s,
                                                    unsigned short* __restrict__ obt) {
    const int h = blockIdx.y, b = blockIdx.z;
    const int tid = threadIdx.x;
    const int lane = tid & 63, wv = tid >> 6;
    const int quad = lane >> 4, lr = lane & 15;
    const int m = blockIdx.x * 64 + wv * 16 + lr;
    const int obase = (quad & 2) << 1;   // 0 or 4

    float vo[2][4] = {{0.f,0.f,0.f,0.f},{0.f,0.f,0.f,0.f}};
    for (int t = 0; t < T_; ++t) {
        const int tb = t * B_ + b;
        const size_t slab = (size_t)(tb * NH_ + h) * 3 * 8192;
        const unsigned long long* ap = abits + ((size_t)(tb * NH_ + h) * 1024 + m) * 4 + (quad & 1) * 2;
        unsigned long long Qa = ap[0];
        unsigned long long Qb = ap[1];

        short8 bs[8];
#pragma unroll
        for (int kt = 0; kt < 8; ++kt) {
            int o = kt * 8 + obase;
            unsigned int a4 = (unsigned int)(Qa >> o) & 15u;
            unsigned int b4 = (unsigned int)(Qb >> o) & 15u;
            union { short8 v; unsigned int w[4]; } u;
            u.w[0] = ((a4 & 1u) ? 0x3F80u : 0u) | ((a4 & 2u) ? 0x3F800000u : 0u);
            u.w[1] = ((a4 & 4u) ? 0x3F80u : 0u) | ((a4 & 8u) ? 0x3F800000u : 0u);
            u.w[2] = ((b4 & 1u) ? 0x3F80u : 0u) | ((b4 & 2u) ? 0x3F800000u : 0u);
            u.w[3] = ((b4 & 4u) ? 0x3F80u : 0u) | ((b4 & 8u) ? 0x3F800000u : 0u);
            bs[kt] = u.v;
        }

#pragma unroll
        for (int dt = 0; dt < 2; ++dt) {
            f32x4 acc2 = (f32x4){0.f, 0.f, 0.f, 0.f};
            const unsigned short* y2p = y2s + slab + (size_t)(dt * 16 + lr) * 256 + quad * 8;
#pragma unroll
            for (int s = 0; s < 3; ++s)
#pragma unroll
                for (int kt = 0; kt < 8; ++kt) {
                    short8 a2 = *(const short8*)(y2p + s * 8192 + kt * 32);
                    acc2 = __builtin_amdgcn_mfma_f32_16x16x32_bf16(a2, bs[kt], acc2, 0, 0, 0);
                }
            ushort4 ob;
#pragma unroll
            for (int r = 0; r < 4; ++r) {
                float v = vo[dt][r];
                v += (acc2[r] - v) * 0.5f;
                bool s = (v >= 1.0f);
                ((unsigned short*)&ob)[r] = s ? 0x3F80 : 0;
                vo[dt][r] = s ? 0.f : v;
            }
            *(ushort4*)(obt + ((size_t)tb * HW + m) * C_ + h * 32 + dt * 16 + quad * 4) = ob;
        }
    }
}

// ---------------- K4: proj GEMM via MFMA + BN2 + residual ----------------
__global__ __launch_bounds__(256) void k_mproj(const unsigned short* __restrict__ obt,
                                               const unsigned short* __restrict__ Wp3,
                                               const float* __restrict__ g2,
                                               const float* __restrict__ b2,
                                               const float* __restrict__ x,
                                               float* __restrict__ out) {
    __shared__ short As[3][64][LDK];
    __shared__ short Bs[128][LDK];
    const int nb = blockIdx.x, mb = blockIdx.y;
    const int tid = threadIdx.x;
    const int lane = tid & 63, wave = tid >> 6;
    const int wm = wave >> 1, wn = wave & 1;
    const int quad = lane >> 4, lr = lane & 15;
    const int arow = tid >> 2, akoff = (tid & 3) * 8;
    f32x4 acc[2][4];
#pragma unroll
    for (int im = 0; im < 2; ++im)
#pragma unroll
        for (int in = 0; in < 4; ++in)
            acc[im][in] = (f32x4){0.f, 0.f, 0.f, 0.f};

    for (int k0 = 0; k0 < 384; k0 += 32) {
#pragma unroll
        for (int s = 0; s < 3; ++s) {
            short8 a = *(const short8*)(Wp3 + ((size_t)(s * 384 + mb * 64 + arow)) * 384 + k0 + akoff);
            *(short8*)&As[s][arow][akoff] = a;
        }
#pragma unroll
        for (int i = 0; i < 2; ++i) {
            int f = i * 256 + tid;
            int row = f >> 2, koff = (f & 3) * 8;
            short8 bv = *(const short8*)(obt + ((size_t)(nb * 128 + row)) * 384 + k0 + koff);
            *(short8*)&Bs[row][koff] = bv;
        }
        __syncthreads();
        short8 bf[4], af[3][2];
#pragma unroll
        for (int in = 0; in < 4; ++in)
            bf[in] = *(const short8*)&Bs[wn * 64 + in * 16 + lr][quad * 8];
#pragma unroll
        for (int s = 0; s < 3; ++s)
#pragma unroll
            for (int im = 0; im < 2; ++im)
                af[s][im] = *(const short8*)&As[s][wm * 32 + im * 16 + lr][quad * 8];
#pragma unroll
        for (int s = 0; s < 3; ++s)
#pragma unroll
            for (int im = 0; im < 2; ++im)
#pragma unroll
                for (int in = 0; in < 4; ++in)
                    acc[im][in] = __builtin_amdgcn_mfma_f32_16x16x32_bf16(af[s][im], bf[in], acc[im][in], 0, 0, 0);
        __syncthreads();
    }
    const float rs = 1.0f / sqrtf(1.0f + EPS_);
#pragma unroll
    for (int im = 0; im < 2; ++im) {
#pragma unroll
        for (int in = 0; in < 4; ++in) {
            int n_g = nb * 128 + wn * 64 + in * 16 + lr;
            int tb = n_g >> 10, hw = n_g & 1023;
#pragma unroll
            for (int r = 0; r < 4; ++r) {
                int o = mb * 64 + wm * 32 + im * 16 + quad * 4 + r;
                size_t idx = ((size_t)tb * C_ + o) * HW + hw;
                out[idx] = acc[im][in][r] * (g2[o] * rs) + b2[o] + x[idx];
            }
        }
    }
}

extern "C" void kernel_launch(void* const* d_in, const int* in_sizes, int n_in,
                              void* d_out, int out_size, void* d_ws, size_t ws_size,
                              hipStream_t stream) {
    const float* x      = (const float*)d_in[0];
    const float* Wconv  = (const float*)d_in[1];
    const float* gamma1 = (const float*)d_in[2];
    const float* beta1  = (const float*)d_in[3];
    const float* Wproj  = (const float*)d_in[4];
    const float* gamma2 = (const float*)d_in[5];
    const float* beta2  = (const float*)d_in[6];
    const float* frx    = (const float*)d_in[7];
    const float* fra    = (const float*)d_in[8];
    float* out = (float*)d_out;

    unsigned short* ws16 = (unsigned short*)d_ws;
    unsigned short* Bc  = ws16;                 // 6,291,456 u16 (aliased by obt after k_mconv)
    unsigned short* obt = ws16;
    unsigned short* Wc3 = ws16 + 6291456;       // 3,538,944
    unsigned short* Wp3 = ws16 + 9830400;       // 442,368
    unsigned short* xsb = ws16 + 10272768;      // 6,291,456
    unsigned short* y1s = ws16 + 16564224;      // 4,718,592
    unsigned short* y2s = ws16 + 21282816;      // 4,718,592
    unsigned long long* abits = (unsigned long long*)(ws16 + 26001408);  // 786,432 u64 = 6.3 MB

    k_wsplit<<<5184, 256, 0, stream>>>(Wconv, Wproj, Wc3, Wp3);
    k_lif_im2col<<<1536, 256, 0, stream>>>(x, Bc, xsb);
    k_mconv<<<dim3(32, 12), 256, 0, stream>>>(Bc, Wc3, gamma1, beta1, frx, fra, y1s, y2s);
    k_attn_qk<<<dim3(16, 12, 4), 256, 0, stream>>>(xsb, y1s, abits);
    k_attn_pv<<<dim3(16, 12, 4), 256, 0, stream>>>(abits, y2s, obt);
    k_mproj<<<dim3(128, 6), 256, 0, stream>>>(obt, Wp3, gamma2, beta2, x, out);
}

// Round 7
// 253.296 us; speedup vs baseline: 1.1904x; 1.1904x over previous
//
#include <hip/hip_runtime.h>
#include <hip/hip_bf16.h>
#include <math.h>

// R7: attention kernels restructured around m-invariant A-fragments.
//   y1/y2 fragments per (tb,h) are the SAME for every m-tile -> wave owns a
//   set of m-tiles, loads fragments once per t (plain LICM, no barriers, no
//   cross-barrier register gamble), and amortizes them over 4x the MFMAs.
//   qk: 12 loads -> 48 MFMA/t/wave.  pv: 24 loads -> 96 MFMA/t/wave.
//   abits bit layout identical to R6 (HW-verified). Other kernels unchanged.

typedef __attribute__((ext_vector_type(8))) short short8;
typedef __attribute__((ext_vector_type(4))) float f32x4;

#define T_ 4
#define B_ 4
#define C_ 384
#define HW 1024
#define NH_ 12
#define Np_ 256
#define EPS_ 1e-5f
#define LDK 56

static __device__ __forceinline__ unsigned short f2bf(float f) {
    __hip_bfloat16 h = __float2bfloat16(f);
    return *reinterpret_cast<unsigned short*>(&h);
}
static __device__ __forceinline__ float bf2f(unsigned short u) {
    __hip_bfloat16 h = *reinterpret_cast<__hip_bfloat16*>(&u);
    return __bfloat162float(h);
}
static __device__ __forceinline__ void split3(float w, unsigned short& u0,
                                              unsigned short& u1, unsigned short& u2) {
    u0 = f2bf(w);  float f0 = bf2f(u0);
    float r1 = w - f0;
    u1 = f2bf(r1); float f1 = bf2f(u1);
    u2 = f2bf(r1 - f1);
}

// ---------------- K0: weight 3-way bf16 split ----------------
__global__ __launch_bounds__(256) void k_wsplit(const float* __restrict__ Wc,
                                                const float* __restrict__ Wp,
                                                unsigned short* __restrict__ Wc3,
                                                unsigned short* __restrict__ Wp3) {
    const int NC = 768 * 1536;
    const int NP = 384 * 384;
    int i = blockIdx.x * 256 + threadIdx.x;
    float w; unsigned short* dst; int idx, plane;
    if (i < NC) { w = Wc[i]; dst = Wc3; idx = i; plane = NC; }
    else {
        int j = i - NC;
        if (j >= NP) return;
        w = Wp[j]; dst = Wp3; idx = j; plane = NP;
    }
    unsigned short u0, u1, u2;
    split3(w, u0, u1, u2);
    dst[idx] = u0; dst[plane + idx] = u1; dst[2 * plane + idx] = u2;
}

// ---------------- K1: LIF(x) fused with im2col -> Bc[n][k] bf16, + xsb[tb][c][hw] bf16 ----
__global__ __launch_bounds__(256) void k_lif_im2col(const float* __restrict__ x,
                                                    unsigned short* __restrict__ Bc,
                                                    unsigned short* __restrict__ xsb) {
    int gt = blockIdx.x * 256 + threadIdx.x;
    int pw = gt & 15, ph = (gt >> 4) & 15;
    int v = gt >> 8;
    int c = v % 384, b = v / 384;
    float v00 = 0.f, v01 = 0.f, v10 = 0.f, v11 = 0.f;
    const size_t xrow = ((size_t)b * C_ + c) * HW + (size_t)(2 * ph) * 32 + 2 * pw;
#pragma unroll
    for (int t = 0; t < T_; ++t) {
        const float* px = x + (size_t)t * (B_ * C_ * HW) + xrow;
        float2 r0 = *(const float2*)px;
        float2 r1 = *(const float2*)(px + 32);
        v00 += (r0.x - v00) * 0.5f;
        v01 += (r0.y - v01) * 0.5f;
        v10 += (r1.x - v10) * 0.5f;
        v11 += (r1.y - v11) * 0.5f;
        ushort4 s;
        s.x = (v00 >= 1.f) ? 0x3F80 : 0; if (v00 >= 1.f) v00 = 0.f;
        s.y = (v01 >= 1.f) ? 0x3F80 : 0; if (v01 >= 1.f) v01 = 0.f;
        s.z = (v10 >= 1.f) ? 0x3F80 : 0; if (v10 >= 1.f) v10 = 0.f;
        s.w = (v11 >= 1.f) ? 0x3F80 : 0; if (v11 >= 1.f) v11 = 0.f;
        int tb = t * B_ + b;
        int n = tb * 256 + ph * 16 + pw;
        *(ushort4*)(Bc + (size_t)n * 1536 + 4 * c) = s;
        size_t xo = ((size_t)tb * C_ + c) * HW + (size_t)(2 * ph) * 32 + 2 * pw;
        ushort2 w0 = {s.x, s.y}, w1 = {s.z, s.w};
        *(ushort2*)(xsb + xo) = w0;
        *(ushort2*)(xsb + xo + 32) = w1;
    }
}

// ---------------- K2: conv GEMM via MFMA; epilogue emits scaled 3-split y1s/y2s ----------
__global__ __launch_bounds__(256) void k_mconv(const unsigned short* __restrict__ Bc,
                                               const unsigned short* __restrict__ Wc3,
                                               const float* __restrict__ g1,
                                               const float* __restrict__ b1,
                                               const float* __restrict__ frx,
                                               const float* __restrict__ fra,
                                               unsigned short* __restrict__ y1s,
                                               unsigned short* __restrict__ y2s) {
    __shared__ short As[3][64][LDK];
    __shared__ short Bs[128][LDK];
    const int nb = blockIdx.x, mb = blockIdx.y;
    const int tid = threadIdx.x;
    const int lane = tid & 63, wave = tid >> 6;
    const int wm = wave >> 1, wn = wave & 1;
    const int quad = lane >> 4, lr = lane & 15;
    const int arow = tid >> 2, akoff = (tid & 3) * 8;
    f32x4 acc[2][4];
#pragma unroll
    for (int im = 0; im < 2; ++im)
#pragma unroll
        for (int in = 0; in < 4; ++in)
            acc[im][in] = (f32x4){0.f, 0.f, 0.f, 0.f};

    for (int k0 = 0; k0 < 1536; k0 += 32) {
#pragma unroll
        for (int s = 0; s < 3; ++s) {
            short8 a = *(const short8*)(Wc3 + ((size_t)(s * 768 + mb * 64 + arow)) * 1536 + k0 + akoff);
            *(short8*)&As[s][arow][akoff] = a;
        }
#pragma unroll
        for (int i = 0; i < 2; ++i) {
            int f = i * 256 + tid;
            int row = f >> 2, koff = (f & 3) * 8;
            short8 bv = *(const short8*)(Bc + ((size_t)(nb * 128 + row)) * 1536 + k0 + koff);
            *(short8*)&Bs[row][koff] = bv;
        }
        __syncthreads();
        short8 bf[4], af[3][2];
#pragma unroll
        for (int in = 0; in < 4; ++in)
            bf[in] = *(const short8*)&Bs[wn * 64 + in * 16 + lr][quad * 8];
#pragma unroll
        for (int s = 0; s < 3; ++s)
#pragma unroll
            for (int im = 0; im < 2; ++im)
                af[s][im] = *(const short8*)&As[s][wm * 32 + im * 16 + lr][quad * 8];
#pragma unroll
        for (int s = 0; s < 3; ++s)
#pragma unroll
            for (int im = 0; im < 2; ++im)
#pragma unroll
                for (int in = 0; in < 4; ++in)
                    acc[im][in] = __builtin_amdgcn_mfma_f32_16x16x32_bf16(af[s][im], bf[in], acc[im][in], 0, 0, 0);
        __syncthreads();
    }
    const float rs = 1.0f / sqrtf(1.0f + EPS_);
    const int h = mb;
    const float scl = (wm == 0) ? (1.0f / sqrtf(frx[h] * 32.0f))
                                : (1.0f / sqrtf(fra[h] * 256.0f));
    unsigned short* dst = (wm == 0) ? y1s : y2s;
#pragma unroll
    for (int im = 0; im < 2; ++im) {
#pragma unroll
        for (int in = 0; in < 4; ++in) {
            int n_g = nb * 128 + wn * 64 + in * 16 + lr;
            int tb = n_g >> 8, pn = n_g & 255;
            size_t base = (size_t)(tb * NH_ + h) * 3 * 8192;
            ushort4 o0, o1, o2;
#pragma unroll
            for (int r = 0; r < 4; ++r) {
                int oc = mb * 64 + wm * 32 + im * 16 + quad * 4 + r;
                float val = (acc[im][in][r] * (g1[oc] * rs) + b1[oc]) * scl;
                unsigned short u0, u1, u2;
                split3(val, u0, u1, u2);
                ((unsigned short*)&o0)[r] = u0;
                ((unsigned short*)&o1)[r] = u1;
                ((unsigned short*)&o2)[r] = u2;
            }
            int dd = im * 16 + quad * 4;
            if (wm == 0) {
                *(ushort4*)&dst[base + 0 * 8192 + (size_t)pn * 32 + dd] = o0;
                *(ushort4*)&dst[base + 1 * 8192 + (size_t)pn * 32 + dd] = o1;
                *(ushort4*)&dst[base + 2 * 8192 + (size_t)pn * 32 + dd] = o2;
            } else {
#pragma unroll
                for (int r = 0; r < 4; ++r) {
                    dst[base + 0 * 8192 + (size_t)(dd + r) * 256 + pn] = ((unsigned short*)&o0)[r];
                    dst[base + 1 * 8192 + (size_t)(dd + r) * 256 + pn] = ((unsigned short*)&o1)[r];
                    dst[base + 2 * 8192 + (size_t)(dd + r) * 256 + pn] = ((unsigned short*)&o2)[r];
                }
            }
        }
    }
}

// ---------------- K3a: ein1 + attn-LIF -> packed spike bits ----------------
// Block = (64 m-cols, h, b); wave wq owns n-range [wq*64, wq*64+64) for ALL
// 4 m-tiles. y1 frags (12) loaded once per t, reused 4x. Bits: lane (quad,lr)
// of m-tile mi covers n = (wq*4+itl)*16 + quad*4 + r -> u16 subword wq of
// abits[tbh][m][quad], local bit itl*4+r (same u64 layout as R6, verified).
__global__ __launch_bounds__(256, 2) void k_attn_qk(const unsigned short* __restrict__ xsb,
                                                    const unsigned short* __restrict__ y1s,
                                                    unsigned short* __restrict__ abq) {
    __shared__ unsigned short xb[4][64][40];   // [t][m][d] : 20,480 B
    const int h = blockIdx.y, b = blockIdx.z;
    const int tid = threadIdx.x;
    const int lane = tid & 63, wq = tid >> 6;
    const int quad = lane >> 4, lr = lane & 15;
    const int m0 = blockIdx.x * 64;

#pragma unroll
    for (int i = 0; i < 8; ++i) {
        int e = tid + i * 256;                 // 2048 ushort4 = 4t*64m*32d
        int j4 = e & 15, d = (e >> 4) & 31, t = e >> 9;
        ushort4 v = *(const ushort4*)(xsb + ((size_t)((t * B_ + b) * C_) + h * 32 + d) * HW + m0 + j4 * 4);
        xb[t][j4 * 4 + 0][d] = v.x;
        xb[t][j4 * 4 + 1][d] = v.y;
        xb[t][j4 * 4 + 2][d] = v.z;
        xb[t][j4 * 4 + 3][d] = v.w;
    }
    __syncthreads();   // only barrier; t/m loops below are wave-autonomous

    float vat[4][4][4];   // [mi][itl][r] attn-LIF state
#pragma unroll
    for (int mi = 0; mi < 4; ++mi)
#pragma unroll
        for (int itl = 0; itl < 4; ++itl)
#pragma unroll
            for (int r = 0; r < 4; ++r) vat[mi][itl][r] = 0.f;

#pragma unroll
    for (int t = 0; t < T_; ++t) {
        const int tb = t * B_ + b;
        const size_t slab = (size_t)(tb * NH_ + h) * 3 * 8192;

        // m-invariant A-fragments: 12 loads, reused by all 4 m-tiles
        short8 af[3][4];
        const unsigned short* y1p = y1s + slab + (size_t)(wq * 64 + lr) * 32 + quad * 8;
#pragma unroll
        for (int s = 0; s < 3; ++s)
#pragma unroll
            for (int itl = 0; itl < 4; ++itl)
                af[s][itl] = *(const short8*)(y1p + s * 8192 + itl * 512);

#pragma unroll
        for (int mi = 0; mi < 4; ++mi) {
            short8 bx = *(const short8*)&xb[t][mi * 16 + lr][quad * 8];
            f32x4 acc[4];
#pragma unroll
            for (int itl = 0; itl < 4; ++itl) acc[itl] = (f32x4){0.f, 0.f, 0.f, 0.f};
#pragma unroll
            for (int s = 0; s < 3; ++s)
#pragma unroll
                for (int itl = 0; itl < 4; ++itl)
                    acc[itl] = __builtin_amdgcn_mfma_f32_16x16x32_bf16(af[s][itl], bx, acc[itl], 0, 0, 0);

            unsigned int q = 0;
#pragma unroll
            for (int itl = 0; itl < 4; ++itl)
#pragma unroll
                for (int r = 0; r < 4; ++r) {
                    float v = vat[mi][itl][r];
                    v += (acc[itl][r] - v) * 0.5f;
                    bool s = (v >= 1.0f);
                    vat[mi][itl][r] = s ? 0.f : v;
                    q |= (s ? 1u : 0u) << (itl * 4 + r);
                }
            int m = m0 + mi * 16 + lr;
            abq[(((size_t)(tb * NH_ + h) * 1024 + m) * 4 + quad) * 4 + wq] = (unsigned short)q;
        }
    }
}

// ---------------- K3b: ein2 + out-LIF (no LDS, no barriers) ----------------
// Block = (128 m-cols, h, b); wave: dt=wv>>1, mg=wv&1 -> owns 4 m-tiles.
// y2 frags (24) loaded once per t, reused 4x (LICM, no barriers in the way).
__global__ __launch_bounds__(256, 1) void k_attn_pv(const unsigned long long* __restrict__ abits,
                                                    const unsigned short* __restrict__ y2s,
                                                    unsigned short* __restrict__ obt) {
    const int h = blockIdx.y, b = blockIdx.z;
    const int tid = threadIdx.x;
    const int lane = tid & 63, wv = tid >> 6;
    const int quad = lane >> 4, lr = lane & 15;
    const int dt = wv >> 1, mg = wv & 1;
    const int mbase = blockIdx.x * 128 + mg * 64;
    const int obase = (quad & 2) << 1;   // 0 or 4

    float vo[4][4];
#pragma unroll
    for (int mi = 0; mi < 4; ++mi)
#pragma unroll
        for (int r = 0; r < 4; ++r) vo[mi][r] = 0.f;

#pragma unroll
    for (int t = 0; t < T_; ++t) {
        const int tb = t * B_ + b;
        const size_t slab = (size_t)(tb * NH_ + h) * 3 * 8192;

        // m-invariant A-fragments: 24 loads, reused by all 4 m-tiles
        short8 ay[3][8];
        const unsigned short* y2p = y2s + slab + (size_t)(dt * 16 + lr) * 256 + quad * 8;
#pragma unroll
        for (int s = 0; s < 3; ++s)
#pragma unroll
            for (int kt = 0; kt < 8; ++kt)
                ay[s][kt] = *(const short8*)(y2p + s * 8192 + kt * 32);

#pragma unroll
        for (int mi = 0; mi < 4; ++mi) {
            const int m = mbase + mi * 16 + lr;
            const unsigned long long* ap = abits + ((size_t)(tb * NH_ + h) * 1024 + m) * 4 + (quad & 1) * 2;
            unsigned long long Qa = ap[0];
            unsigned long long Qb = ap[1];

            short8 bs[8];
#pragma unroll
            for (int kt = 0; kt < 8; ++kt) {
                int o = kt * 8 + obase;
                unsigned int a4 = (unsigned int)(Qa >> o) & 15u;
                unsigned int b4 = (unsigned int)(Qb >> o) & 15u;
                union { short8 v; unsigned int w[4]; } u;
                u.w[0] = ((a4 & 1u) ? 0x3F80u : 0u) | ((a4 & 2u) ? 0x3F800000u : 0u);
                u.w[1] = ((a4 & 4u) ? 0x3F80u : 0u) | ((a4 & 8u) ? 0x3F800000u : 0u);
                u.w[2] = ((b4 & 1u) ? 0x3F80u : 0u) | ((b4 & 2u) ? 0x3F800000u : 0u);
                u.w[3] = ((b4 & 4u) ? 0x3F80u : 0u) | ((b4 & 8u) ? 0x3F800000u : 0u);
                bs[kt] = u.v;
            }

            f32x4 acc2 = (f32x4){0.f, 0.f, 0.f, 0.f};
#pragma unroll
            for (int s = 0; s < 3; ++s)
#pragma unroll
                for (int kt = 0; kt < 8; ++kt)
                    acc2 = __builtin_amdgcn_mfma_f32_16x16x32_bf16(ay[s][kt], bs[kt], acc2, 0, 0, 0);

            ushort4 ob;
#pragma unroll
            for (int r = 0; r < 4; ++r) {
                float v = vo[mi][r];
                v += (acc2[r] - v) * 0.5f;
                bool s = (v >= 1.0f);
                ((unsigned short*)&ob)[r] = s ? 0x3F80 : 0;
                vo[mi][r] = s ? 0.f : v;
            }
            *(ushort4*)(obt + ((size_t)tb * HW + m) * C_ + h * 32 + dt * 16 + quad * 4) = ob;
        }
    }
}

// ---------------- K4: proj GEMM via MFMA + BN2 + residual ----------------
__global__ __launch_bounds__(256) void k_mproj(const unsigned short* __restrict__ obt,
                                               const unsigned short* __restrict__ Wp3,
                                               const float* __restrict__ g2,
                                               const float* __restrict__ b2,
                                               const float* __restrict__ x,
                                               float* __restrict__ out) {
    __shared__ short As[3][64][LDK];
    __shared__ short Bs[128][LDK];
    const int nb = blockIdx.x, mb = blockIdx.y;
    const int tid = threadIdx.x;
    const int lane = tid & 63, wave = tid >> 6;
    const int wm = wave >> 1, wn = wave & 1;
    const int quad = lane >> 4, lr = lane & 15;
    const int arow = tid >> 2, akoff = (tid & 3) * 8;
    f32x4 acc[2][4];
#pragma unroll
    for (int im = 0; im < 2; ++im)
#pragma unroll
        for (int in = 0; in < 4; ++in)
            acc[im][in] = (f32x4){0.f, 0.f, 0.f, 0.f};

    for (int k0 = 0; k0 < 384; k0 += 32) {
#pragma unroll
        for (int s = 0; s < 3; ++s) {
            short8 a = *(const short8*)(Wp3 + ((size_t)(s * 384 + mb * 64 + arow)) * 384 + k0 + akoff);
            *(short8*)&As[s][arow][akoff] = a;
        }
#pragma unroll
        for (int i = 0; i < 2; ++i) {
            int f = i * 256 + tid;
            int row = f >> 2, koff = (f & 3) * 8;
            short8 bv = *(const short8*)(obt + ((size_t)(nb * 128 + row)) * 384 + k0 + koff);
            *(short8*)&Bs[row][koff] = bv;
        }
        __syncthreads();
        short8 bf[4], af[3][2];
#pragma unroll
        for (int in = 0; in < 4; ++in)
            bf[in] = *(const short8*)&Bs[wn * 64 + in * 16 + lr][quad * 8];
#pragma unroll
        for (int s = 0; s < 3; ++s)
#pragma unroll
            for (int im = 0; im < 2; ++im)
                af[s][im] = *(const short8*)&As[s][wm * 32 + im * 16 + lr][quad * 8];
#pragma unroll
        for (int s = 0; s < 3; ++s)
#pragma unroll
            for (int im = 0; im < 2; ++im)
#pragma unroll
                for (int in = 0; in < 4; ++in)
                    acc[im][in] = __builtin_amdgcn_mfma_f32_16x16x32_bf16(af[s][im], bf[in], acc[im][in], 0, 0, 0);
        __syncthreads();
    }
    const float rs = 1.0f / sqrtf(1.0f + EPS_);
#pragma unroll
    for (int im = 0; im < 2; ++im) {
#pragma unroll
        for (int in = 0; in < 4; ++in) {
            int n_g = nb * 128 + wn * 64 + in * 16 + lr;
            int tb = n_g >> 10, hw = n_g & 1023;
#pragma unroll
            for (int r = 0; r < 4; ++r) {
                int o = mb * 64 + wm * 32 + im * 16 + quad * 4 + r;
                size_t idx = ((size_t)tb * C_ + o) * HW + hw;
                out[idx] = acc[im][in][r] * (g2[o] * rs) + b2[o] + x[idx];
            }
        }
    }
}

extern "C" void kernel_launch(void* const* d_in, const int* in_sizes, int n_in,
                              void* d_out, int out_size, void* d_ws, size_t ws_size,
                              hipStream_t stream) {
    const float* x      = (const float*)d_in[0];
    const float* Wconv  = (const float*)d_in[1];
    const float* gamma1 = (const float*)d_in[2];
    const float* beta1  = (const float*)d_in[3];
    const float* Wproj  = (const float*)d_in[4];
    const float* gamma2 = (const float*)d_in[5];
    const float* beta2  = (const float*)d_in[6];
    const float* frx    = (const float*)d_in[7];
    const float* fra    = (const float*)d_in[8];
    float* out = (float*)d_out;

    unsigned short* ws16 = (unsigned short*)d_ws;
    unsigned short* Bc  = ws16;                 // 6,291,456 u16 (aliased by obt after k_mconv)
    unsigned short* obt = ws16;
    unsigned short* Wc3 = ws16 + 6291456;       // 3,538,944
    unsigned short* Wp3 = ws16 + 9830400;       // 442,368
    unsigned short* xsb = ws16 + 10272768;      // 6,291,456
    unsigned short* y1s = ws16 + 16564224;      // 4,718,592
    unsigned short* y2s = ws16 + 21282816;      // 4,718,592
    unsigned long long* abits = (unsigned long long*)(ws16 + 26001408);  // 786,432 u64 = 6.3 MB

    k_wsplit<<<5184, 256, 0, stream>>>(Wconv, Wproj, Wc3, Wp3);
    k_lif_im2col<<<1536, 256, 0, stream>>>(x, Bc, xsb);
    k_mconv<<<dim3(32, 12), 256, 0, stream>>>(Bc, Wc3, gamma1, beta1, frx, fra, y1s, y2s);
    k_attn_qk<<<dim3(16, 12, 4), 256, 0, stream>>>(xsb, y1s, (unsigned short*)abits);
    k_attn_pv<<<dim3(8, 12, 4), 256, 0, stream>>>(abits, y2s, obt);
    k_mproj<<<dim3(128, 6), 256, 0, stream>>>(obt, Wp3, gamma2, beta2, x, out);
}